// Round 2
// baseline (27930.493 us; speedup 1.0000x reference)
//
#include <hip/hip_runtime.h>

#define V 256
#define H 2048
#define A 512
#define S 512
#define NBLK 256
#define NTHR 512

// ---------------- grid barrier (sense-reversing, agent scope) ----------------
__device__ __forceinline__ void grid_barrier(int* cnt, int* sense, int* epoch_io) {
    __syncthreads();
    if (threadIdx.x == 0) {
        const int e = ++(*epoch_io);
        __threadfence();  // release: publish this block's stores
        int prev = __hip_atomic_fetch_add(cnt, 1, __ATOMIC_ACQ_REL, __HIP_MEMORY_SCOPE_AGENT);
        if (prev == NBLK - 1) {
            __hip_atomic_store(cnt, 0, __ATOMIC_RELAXED, __HIP_MEMORY_SCOPE_AGENT);
            __hip_atomic_store(sense, e, __ATOMIC_RELEASE, __HIP_MEMORY_SCOPE_AGENT); // orders cnt reset before release
        } else {
            // RELAXED poll (an acquire per poll would spam cache invalidates)
            while (__hip_atomic_load(sense, __ATOMIC_RELAXED, __HIP_MEMORY_SCOPE_AGENT) < e)
                __builtin_amdgcn_s_sleep(2);
        }
        __threadfence();  // acquire: invalidate stale lines once
    }
    __syncthreads();
}

__global__ void init_bar(int* bar) {
    bar[0] = 0; bar[64] = 0; bar[128] = 0; bar[192] = 0;
}

// ---------------- generic NT GEMM (unchanged from R1) ----------------
__global__ __launch_bounds__(256) void gemm_nt(
    const float* __restrict__ Amat, int lda,
    const float* __restrict__ Bmat, int ldb,
    float* __restrict__ C, int ldc,
    const float* __restrict__ bias, int M, int N, int K)
{
    __shared__ float As[16][68];
    __shared__ float Bs[16][68];
    const int tid = threadIdx.x;
    const int tx = tid & 15;
    const int ty = tid >> 4;
    const int m0 = blockIdx.y * 64;
    const int n0 = blockIdx.x * 64;
    const int lr = tid >> 2;
    const int lk = (tid & 3) * 4;

    float acc[4][4] = {};
    for (int k0 = 0; k0 < K; k0 += 16) {
        float4 av = *(const float4*)(Amat + (size_t)(m0 + lr) * lda + k0 + lk);
        float4 bv = *(const float4*)(Bmat + (size_t)(n0 + lr) * ldb + k0 + lk);
        __syncthreads();
        As[lk+0][lr] = av.x; As[lk+1][lr] = av.y; As[lk+2][lr] = av.z; As[lk+3][lr] = av.w;
        Bs[lk+0][lr] = bv.x; Bs[lk+1][lr] = bv.y; Bs[lk+2][lr] = bv.z; Bs[lk+3][lr] = bv.w;
        __syncthreads();
        #pragma unroll
        for (int k = 0; k < 16; ++k) {
            float a4[4], b4[4];
            #pragma unroll
            for (int i = 0; i < 4; ++i) a4[i] = As[k][ty*4+i];
            #pragma unroll
            for (int j = 0; j < 4; ++j) b4[j] = Bs[k][tx*4+j];
            #pragma unroll
            for (int i = 0; i < 4; ++i)
                #pragma unroll
                for (int j = 0; j < 4; ++j) acc[i][j] += a4[i] * b4[j];
        }
    }
    #pragma unroll
    for (int i = 0; i < 4; ++i) {
        const int m = m0 + ty*4 + i;
        #pragma unroll
        for (int j = 0; j < 4; ++j) {
            const int n = n0 + tx*4 + j;
            float v = acc[i][j];
            if (bias) v += bias[n];
            C[(size_t)m * ldc + n] = v;
        }
    }
}

// ---------------- persistent encoder scan ----------------
__global__ __launch_bounds__(NTHR, 1) void enc_scan(
    const float* __restrict__ W_enc, const float* __restrict__ accx,
    float* __restrict__ states, int* cnt, int* sense)
{
    __shared__ __align__(16) float hs[H];
    const int tid = threadIdx.x;
    const int wid = tid >> 6, lane = tid & 63;
    const int row = blockIdx.x * 8 + wid;        // 0..H-1, one wave per row
    const float4* w4 = (const float4*)(W_enc + (size_t)row * (V + H) + V);
    int epoch = 0;

    // t = 0: h = tanh(accx) (h_prev is zero)
    if (lane == 0) states[row] = tanhf(accx[row]);

    for (int t = 1; t < S; ++t) {
        grid_barrier(cnt, sense, &epoch);        // states[t-1] now globally visible
        ((float4*)hs)[tid] = ((const float4*)(states + (size_t)(t-1)*H))[tid];
        __syncthreads();
        const float4* h4 = (const float4*)hs;
        float acc = 0.f;
        #pragma unroll
        for (int it = 0; it < 8; ++it) {
            float4 w  = w4[lane + it*64];
            float4 hh = h4[lane + it*64];
            acc += w.x*hh.x + w.y*hh.y + w.z*hh.z + w.w*hh.w;
        }
        #pragma unroll
        for (int off = 32; off; off >>= 1) acc += __shfl_down(acc, off);
        if (lane == 0) states[(size_t)t*H + row] = tanhf(acc + accx[(size_t)t*H + row]);
    }
}

// ---------------- persistent decoder scan ----------------
__global__ __launch_bounds__(NTHR, 1) void dec_scan(
    const float* __restrict__ Wa_dec, const float* __restrict__ W_dec,
    const float* __restrict__ enc_proj, const float* __restrict__ v_a,
    const float* __restrict__ WcT, const float* __restrict__ accx,
    const float* __restrict__ enc_states, float* __restrict__ h_dec,
    float* __restrict__ dec_proj, float* __restrict__ evec,
    int* cnt, int* sense)
{
    __shared__ __align__(16) float hs[H];
    __shared__ __align__(16) float ps[A];
    __shared__ __align__(16) float vs[A];
    __shared__ __align__(16) float es[S];
    __shared__ float zred[8];
    const int tid = threadIdx.x;
    const int wid = tid >> 6, lane = tid & 63;
    const int gw  = blockIdx.x * 8 + wid;        // 0..2047
    int epoch = 0;

    if (tid < A/4) ((float4*)vs)[tid] = ((const float4*)v_a)[tid];

    const float4* wd4 = (const float4*)(W_dec + (size_t)gw * (V + 2*H) + V + H);  // W_h row
    const float4* wa4 = (const float4*)(Wa_dec + (size_t)gw * H);                 // valid if gw<A
    const float4* wc4 = (const float4*)(WcT + (size_t)gw * S);

    for (int t = 0; t < S; ++t) {
        // ---- stage h_{t-1} ----
        const float* hsrc = t ? (h_dec + (size_t)(t-1)*H) : (enc_states + (size_t)(S-1)*H);
        ((float4*)hs)[tid] = ((const float4*)hsrc)[tid];
        __syncthreads();

        // ---- P1: accH = W_h[gw]·h (register-resident); dec_proj[gw] for gw<A ----
        const float4* h4 = (const float4*)hs;
        float accH = 0.f, accP = 0.f;
        if (gw < A) {
            #pragma unroll
            for (int it = 0; it < 8; ++it) {
                float4 hh = h4[lane + it*64];
                float4 w  = wd4[lane + it*64];
                float4 wa = wa4[lane + it*64];
                accH += w.x*hh.x + w.y*hh.y + w.z*hh.z + w.w*hh.w;
                accP += wa.x*hh.x + wa.y*hh.y + wa.z*hh.z + wa.w*hh.w;
            }
        } else {
            #pragma unroll
            for (int it = 0; it < 8; ++it) {
                float4 hh = h4[lane + it*64];
                float4 w  = wd4[lane + it*64];
                accH += w.x*hh.x + w.y*hh.y + w.z*hh.z + w.w*hh.w;
            }
        }
        #pragma unroll
        for (int off = 32; off; off >>= 1) {
            accH += __shfl_down(accH, off);
            accP += __shfl_down(accP, off);
        }
        if (gw < A && lane == 0) dec_proj[gw] = accP;
        grid_barrier(cnt, sense, &epoch);

        // ---- P2: e[s] = exp(v·tanh(enc_proj[s] + dec_proj)) for s = gw < S ----
        if (tid < A/4) ((float4*)ps)[tid] = ((const float4*)dec_proj)[tid];
        __syncthreads();
        if (gw < S) {
            const float4* ep4 = (const float4*)(enc_proj + (size_t)gw * A);
            float e_ = 0.f;
            #pragma unroll
            for (int it = 0; it < 2; ++it) {
                float4 p  = ep4[lane + it*64];
                float4 d  = ((const float4*)ps)[lane + it*64];
                float4 vv = ((const float4*)vs)[lane + it*64];
                e_ += tanhf(p.x+d.x)*vv.x + tanhf(p.y+d.y)*vv.y
                    + tanhf(p.z+d.z)*vv.z + tanhf(p.w+d.w)*vv.w;
            }
            #pragma unroll
            for (int off = 32; off; off >>= 1) e_ += __shfl_down(e_, off);
            if (lane == 0) evec[gw] = expf(e_);
        }
        grid_barrier(cnt, sense, &epoch);

        // ---- P3: Z, context via WcT·e, h_new ----
        if (tid < S/4) ((float4*)es)[tid] = ((const float4*)evec)[tid];
        __syncthreads();
        float z = es[tid];                       // NTHR == S
        #pragma unroll
        for (int off = 32; off; off >>= 1) z += __shfl_down(z, off);
        if (lane == 0) zred[wid] = z;
        __syncthreads();
        float Z = 0.f;
        #pragma unroll
        for (int i = 0; i < 8; ++i) Z += zred[i];
        const float Zinv = 1.f / Z;

        float ctx = 0.f;
        #pragma unroll
        for (int it = 0; it < 2; ++it) {
            float4 w  = wc4[lane + it*64];
            float4 ee = ((const float4*)es)[lane + it*64];
            ctx += w.x*ee.x + w.y*ee.y + w.z*ee.z + w.w*ee.w;
        }
        #pragma unroll
        for (int off = 32; off; off >>= 1) ctx += __shfl_down(ctx, off);
        if (lane == 0)
            h_dec[(size_t)t*H + gw] = tanhf(accx[(size_t)t*H + gw] + accH + ctx * Zinv);
        grid_barrier(cnt, sense, &epoch);        // h_dec[t] visible for next P1
    }
}

extern "C" void kernel_launch(void* const* d_in, const int* in_sizes, int n_in,
                              void* d_out, int out_size, void* d_ws, size_t ws_size,
                              hipStream_t stream) {
    const float* x_enc  = (const float*)d_in[0];
    const float* x_dec  = (const float*)d_in[1];
    const float* W_enc  = (const float*)d_in[2];
    const float* b_enc  = (const float*)d_in[3];
    const float* Wa_enc = (const float*)d_in[4];
    const float* Wa_dec = (const float*)d_in[5];
    const float* v_a    = (const float*)d_in[6];
    const float* W_dec  = (const float*)d_in[7];
    const float* b_dec  = (const float*)d_in[8];
    const float* W_out  = (const float*)d_in[9];
    const float* b_out  = (const float*)d_in[10];
    float* out = (float*)d_out;

    float* ws         = (float*)d_ws;
    float* accx_enc   = ws;                          // S*H
    float* enc_states = accx_enc + (size_t)S*H;      // S*H
    float* enc_proj   = enc_states + (size_t)S*H;    // S*A
    float* WcT        = enc_proj + (size_t)S*A;      // H*S
    float* accx_dec   = WcT + (size_t)H*S;           // S*H
    float* h_dec      = accx_dec + (size_t)S*H;      // S*H
    float* dec_proj   = h_dec + (size_t)S*H;         // A
    float* evec       = dec_proj + A;                // S
    int*   bar        = (int*)(evec + S);            // 256 ints (4 slots, cacheline-spread)
    int* cnt_e = bar,        * sen_e = bar + 64;
    int* cnt_d = bar + 128,  * sen_d = bar + 192;

    dim3 b256(256);

    init_bar<<<1, 1, 0, stream>>>(bar);

    // accx_enc = x_enc @ W_enc[:, :V].T + b_enc
    gemm_nt<<<dim3(H/64, S/64), b256, 0, stream>>>(x_enc, V, W_enc, V+H, accx_enc, H, b_enc, S, H, V);
    // accx_dec = x_dec @ W_dec[:, :V].T + b_dec
    gemm_nt<<<dim3(H/64, S/64), b256, 0, stream>>>(x_dec, V, W_dec, V+2*H, accx_dec, H, b_dec, S, H, V);

    // encoder scan (cooperative)
    {
        const float* We = W_enc; const float* ax = accx_enc; float* st = enc_states;
        void* args[] = { &We, &ax, &st, &cnt_e, &sen_e };
        hipLaunchCooperativeKernel((void*)enc_scan, dim3(NBLK), dim3(NTHR), args, 0, stream);
    }

    // enc_proj = enc_states @ Wa_enc.T
    gemm_nt<<<dim3(A/64, S/64), b256, 0, stream>>>(enc_states, H, Wa_enc, H, enc_proj, A, nullptr, S, A, H);
    // WcT[i][s] = W_c[i]·enc_states[s]
    gemm_nt<<<dim3(S/64, H/64), b256, 0, stream>>>(W_dec + V, V+2*H, enc_states, H, WcT, S, nullptr, H, S, H);

    // decoder scan (cooperative)
    {
        const float* wa = Wa_dec; const float* wd = W_dec; const float* ep = enc_proj;
        const float* va = v_a; const float* wc = WcT; const float* ax = accx_dec;
        const float* es = enc_states; float* hd = h_dec; float* dp = dec_proj; float* ev = evec;
        void* args[] = { &wa, &wd, &ep, &va, &wc, &ax, &es, &hd, &dp, &ev, &cnt_d, &sen_d };
        hipLaunchCooperativeKernel((void*)dec_scan, dim3(NBLK), dim3(NTHR), args, 0, stream);
    }

    // logits = h_dec @ W_out.T + b_out
    gemm_nt<<<dim3(V/64, S/64), b256, 0, stream>>>(h_dec, H, W_out, H, out, V, b_out, S, V, H);
}

// Round 3
// 6806.247 us; speedup vs baseline: 4.1037x; 4.1037x over previous
//
#include <hip/hip_runtime.h>

#define V 256
#define H 2048
#define A 512
#define S 512
#define NBLK 128
#define NTHR 512

typedef float f32x4 __attribute__((ext_vector_type(4)));
typedef float f32x2 __attribute__((ext_vector_type(2)));

// ---- coherent (L1/L2-bypass, write-through) access helpers: payloads only ----
__device__ __forceinline__ f32x4 ldg_cg4(const float* p) {
    f32x4 r;
    asm volatile("global_load_dwordx4 %0, %1, off sc0 sc1\n\ts_waitcnt vmcnt(0)"
                 : "=v"(r) : "v"(p) : "memory");
    return r;
}
__device__ __forceinline__ void stg_cg1(float* p, float v) {
    asm volatile("global_store_dword %0, %1, off sc0 sc1" :: "v"(p), "v"(v) : "memory");
}
__device__ __forceinline__ void stg_cg2(float* p, f32x2 v) {
    asm volatile("global_store_dwordx2 %0, %1, off sc0 sc1" :: "v"(p), "v"(v) : "memory");
}

// ---- fence-free monotonic 2-level grid barrier ----
// layout within a barrier set: leaf[g] at base[g*64] (g=0..7), top at base[512], sense at base[576]
__device__ __forceinline__ void gbar(int* base, int e) {
    __syncthreads();
    if (threadIdx.x == 0) {
        asm volatile("s_waitcnt vmcnt(0)" ::: "memory");   // payload (sc1 write-through) now globally visible
        int* leaf = base + ((blockIdx.x & 7) << 6);
        int prev = __hip_atomic_fetch_add(leaf, 1, __ATOMIC_RELAXED, __HIP_MEMORY_SCOPE_AGENT);
        if (prev == e * (NBLK / 8) - 1) {
            int p2 = __hip_atomic_fetch_add(base + 512, 1, __ATOMIC_RELAXED, __HIP_MEMORY_SCOPE_AGENT);
            if (p2 == e * 8 - 1)
                __hip_atomic_store(base + 576, e, __ATOMIC_RELAXED, __HIP_MEMORY_SCOPE_AGENT);
        }
        while (__hip_atomic_load(base + 576, __ATOMIC_RELAXED, __HIP_MEMORY_SCOPE_AGENT) < e)
            __builtin_amdgcn_s_sleep(1);
    }
    __syncthreads();
}

__global__ void init_bar(int* bar) {
    for (int i = threadIdx.x; i < 2048; i += blockDim.x) bar[i] = 0;
}

// ---------------- generic NT GEMM (unchanged) ----------------
__global__ __launch_bounds__(256) void gemm_nt(
    const float* __restrict__ Amat, int lda,
    const float* __restrict__ Bmat, int ldb,
    float* __restrict__ C, int ldc,
    const float* __restrict__ bias, int M, int N, int K)
{
    __shared__ float As[16][68];
    __shared__ float Bs[16][68];
    const int tid = threadIdx.x;
    const int tx = tid & 15;
    const int ty = tid >> 4;
    const int m0 = blockIdx.y * 64;
    const int n0 = blockIdx.x * 64;
    const int lr = tid >> 2;
    const int lk = (tid & 3) * 4;

    float acc[4][4] = {};
    for (int k0 = 0; k0 < K; k0 += 16) {
        float4 av = *(const float4*)(Amat + (size_t)(m0 + lr) * lda + k0 + lk);
        float4 bv = *(const float4*)(Bmat + (size_t)(n0 + lr) * ldb + k0 + lk);
        __syncthreads();
        As[lk+0][lr] = av.x; As[lk+1][lr] = av.y; As[lk+2][lr] = av.z; As[lk+3][lr] = av.w;
        Bs[lk+0][lr] = bv.x; Bs[lk+1][lr] = bv.y; Bs[lk+2][lr] = bv.z; Bs[lk+3][lr] = bv.w;
        __syncthreads();
        #pragma unroll
        for (int k = 0; k < 16; ++k) {
            float a4[4], b4[4];
            #pragma unroll
            for (int i = 0; i < 4; ++i) a4[i] = As[k][ty*4+i];
            #pragma unroll
            for (int j = 0; j < 4; ++j) b4[j] = Bs[k][tx*4+j];
            #pragma unroll
            for (int i = 0; i < 4; ++i)
                #pragma unroll
                for (int j = 0; j < 4; ++j) acc[i][j] += a4[i] * b4[j];
        }
    }
    #pragma unroll
    for (int i = 0; i < 4; ++i) {
        const int m = m0 + ty*4 + i;
        #pragma unroll
        for (int j = 0; j < 4; ++j) {
            const int n = n0 + tx*4 + j;
            float v = acc[i][j];
            if (bias) v += bias[n];
            C[(size_t)m * ldc + n] = v;
        }
    }
}

// ---------------- persistent encoder scan: W rows live in registers ----------------
__global__ __launch_bounds__(NTHR, 2) void enc_scan(
    const float* __restrict__ W_enc, const float* __restrict__ accx,
    float* __restrict__ states, int* bar)
{
    __shared__ __align__(16) float hs[H];
    const int tid = threadIdx.x;
    const int wid = tid >> 6, lane = tid & 63;
    const int w   = blockIdx.x * 8 + wid;     // 0..1023
    const int r0  = 2*w, r1 = 2*w + 1;
    int epoch = 0;

    f32x4 we0[8], we1[8];
    #pragma unroll
    for (int k = 0; k < 8; ++k) {
        we0[k] = *(const f32x4*)(W_enc + (size_t)r0*(V+H) + V + 4*(lane + 64*k));
        we1[k] = *(const f32x4*)(W_enc + (size_t)r1*(V+H) + V + 4*(lane + 64*k));
    }
    const f32x4* hs4 = (const f32x4*)hs;

    // t = 0: h = tanh(accx)
    if (lane == 0) {
        f32x2 h0; h0.x = tanhf(accx[r0]); h0.y = tanhf(accx[r1]);
        stg_cg2(states + 2*w, h0);
    }

    for (int t = 1; t < S; ++t) {
        gbar(bar, ++epoch);                   // states[t-1] globally visible
        ((f32x4*)hs)[tid] = ldg_cg4(states + (size_t)(t-1)*H + 4*tid);
        __syncthreads();
        float a0 = 0.f, a1 = 0.f;
        #pragma unroll
        for (int k = 0; k < 8; ++k) {
            f32x4 hv = hs4[lane + 64*k];
            a0 += we0[k].x*hv.x + we0[k].y*hv.y + we0[k].z*hv.z + we0[k].w*hv.w;
            a1 += we1[k].x*hv.x + we1[k].y*hv.y + we1[k].z*hv.z + we1[k].w*hv.w;
        }
        #pragma unroll
        for (int off = 32; off; off >>= 1) { a0 += __shfl_down(a0, off); a1 += __shfl_down(a1, off); }
        if (lane == 0) {
            f32x2 hv;
            hv.x = tanhf(a0 + accx[(size_t)t*H + r0]);
            hv.y = tanhf(a1 + accx[(size_t)t*H + r1]);
            stg_cg2(states + (size_t)t*H + 2*w, hv);
        }
    }
}

// ---------------- persistent decoder scan: all weights in registers ----------------
__global__ __launch_bounds__(NTHR, 2) void dec_scan(
    const float* __restrict__ Wa_dec, const float* __restrict__ W_dec,
    const float* __restrict__ enc_proj, const float* __restrict__ v_a,
    const float* __restrict__ WcT, const float* __restrict__ accx,
    const float* __restrict__ enc_states, float* __restrict__ h_dec,
    float* __restrict__ dec_proj, float* __restrict__ evec,
    int* bar)
{
    __shared__ __align__(16) float hs[H];
    __shared__ __align__(16) float ps[A];
    __shared__ __align__(16) float es[S];
    __shared__ float zred[8];
    const int tid = threadIdx.x;
    const int wid = tid >> 6, lane = tid & 63;
    const int w   = blockIdx.x * 8 + wid;     // 0..1023
    const int r0  = 2*w, r1 = 2*w + 1;
    int epoch = 0;

    f32x4 wh0[8], wh1[8], wa[8], wc0[2], wc1[2], ep[2], va[2];
    #pragma unroll
    for (int k = 0; k < 8; ++k) {
        wh0[k] = *(const f32x4*)(W_dec + (size_t)r0*(V+2*H) + V + H + 4*(lane + 64*k));
        wh1[k] = *(const f32x4*)(W_dec + (size_t)r1*(V+2*H) + V + H + 4*(lane + 64*k));
        wa[k]  = (f32x4)(0.f);
    }
    #pragma unroll
    for (int k = 0; k < 2; ++k) {
        wc0[k] = *(const f32x4*)(WcT + (size_t)r0*S + 4*(lane + 64*k));
        wc1[k] = *(const f32x4*)(WcT + (size_t)r1*S + 4*(lane + 64*k));
        ep[k] = (f32x4)(0.f); va[k] = (f32x4)(0.f);
    }
    if (w < A) {
        #pragma unroll
        for (int k = 0; k < 8; ++k)
            wa[k] = *(const f32x4*)(Wa_dec + (size_t)w*H + 4*(lane + 64*k));
        #pragma unroll
        for (int k = 0; k < 2; ++k) {
            ep[k] = *(const f32x4*)(enc_proj + (size_t)w*A + 4*(lane + 64*k));
            va[k] = *(const f32x4*)(v_a + 4*(lane + 64*k));
        }
    }
    const f32x4* hs4 = (const f32x4*)hs;
    const f32x4* ps4 = (const f32x4*)ps;
    const f32x4* es4 = (const f32x4*)es;

    for (int t = 0; t < S; ++t) {
        // ---- stage h_{t-1} (coherent) ----
        const float* hsrc = t ? (h_dec + (size_t)(t-1)*H) : (enc_states + (size_t)(S-1)*H);
        ((f32x4*)hs)[tid] = ldg_cg4(hsrc + 4*tid);
        __syncthreads();

        // ---- P1: accH (2 rows, reg W_h) + dec_proj row (reg Wa) ----
        float aH0 = 0.f, aH1 = 0.f, aP = 0.f;
        #pragma unroll
        for (int k = 0; k < 8; ++k) {
            f32x4 hv = hs4[lane + 64*k];
            aH0 += wh0[k].x*hv.x + wh0[k].y*hv.y + wh0[k].z*hv.z + wh0[k].w*hv.w;
            aH1 += wh1[k].x*hv.x + wh1[k].y*hv.y + wh1[k].z*hv.z + wh1[k].w*hv.w;
            aP  += wa[k].x*hv.x  + wa[k].y*hv.y  + wa[k].z*hv.z  + wa[k].w*hv.w;
        }
        #pragma unroll
        for (int off = 32; off; off >>= 1) {
            aH0 += __shfl_down(aH0, off);
            aH1 += __shfl_down(aH1, off);
            aP  += __shfl_down(aP,  off);
        }
        if (w < A && lane == 0) stg_cg1(dec_proj + w, aP);
        gbar(bar, ++epoch);

        // ---- P2: e[s=w] = exp(v · tanh(enc_proj[s] + dp)) ----
        if (tid < A/4) ((f32x4*)ps)[tid] = ldg_cg4(dec_proj + 4*tid);
        __syncthreads();
        if (w < S) {
            float e_ = 0.f;
            #pragma unroll
            for (int k = 0; k < 2; ++k) {
                f32x4 p = ps4[lane + 64*k];
                e_ += va[k].x*tanhf(ep[k].x + p.x) + va[k].y*tanhf(ep[k].y + p.y)
                    + va[k].z*tanhf(ep[k].z + p.z) + va[k].w*tanhf(ep[k].w + p.w);
            }
            #pragma unroll
            for (int off = 32; off; off >>= 1) e_ += __shfl_down(e_, off);
            if (lane == 0) stg_cg1(evec + w, expf(e_));
        }
        gbar(bar, ++epoch);

        // ---- P3: Z, ctx (reg WcT), h_new ----
        if (tid < S/4) ((f32x4*)es)[tid] = ldg_cg4(evec + 4*tid);
        __syncthreads();
        float z = es[tid];
        #pragma unroll
        for (int off = 32; off; off >>= 1) z += __shfl_down(z, off);
        if (lane == 0) zred[wid] = z;
        __syncthreads();
        const float Z = zred[0]+zred[1]+zred[2]+zred[3]+zred[4]+zred[5]+zred[6]+zred[7];
        float c0 = 0.f, c1 = 0.f;
        #pragma unroll
        for (int k = 0; k < 2; ++k) {
            f32x4 ev = es4[lane + 64*k];
            c0 += wc0[k].x*ev.x + wc0[k].y*ev.y + wc0[k].z*ev.z + wc0[k].w*ev.w;
            c1 += wc1[k].x*ev.x + wc1[k].y*ev.y + wc1[k].z*ev.z + wc1[k].w*ev.w;
        }
        #pragma unroll
        for (int off = 32; off; off >>= 1) { c0 += __shfl_down(c0, off); c1 += __shfl_down(c1, off); }
        if (lane == 0) {
            const float Zi = 1.f / Z;
            f32x2 hv;
            hv.x = tanhf(accx[(size_t)t*H + r0] + aH0 + c0*Zi);
            hv.y = tanhf(accx[(size_t)t*H + r1] + aH1 + c1*Zi);
            stg_cg2(h_dec + (size_t)t*H + 2*w, hv);
        }
        if (t < S-1) gbar(bar, ++epoch);
    }
}

extern "C" void kernel_launch(void* const* d_in, const int* in_sizes, int n_in,
                              void* d_out, int out_size, void* d_ws, size_t ws_size,
                              hipStream_t stream) {
    const float* x_enc  = (const float*)d_in[0];
    const float* x_dec  = (const float*)d_in[1];
    const float* W_enc  = (const float*)d_in[2];
    const float* b_enc  = (const float*)d_in[3];
    const float* Wa_enc = (const float*)d_in[4];
    const float* Wa_dec = (const float*)d_in[5];
    const float* v_a    = (const float*)d_in[6];
    const float* W_dec  = (const float*)d_in[7];
    const float* b_dec  = (const float*)d_in[8];
    const float* W_out  = (const float*)d_in[9];
    const float* b_out  = (const float*)d_in[10];
    float* out = (float*)d_out;

    float* ws         = (float*)d_ws;
    float* accx_enc   = ws;                          // S*H
    float* enc_states = accx_enc + (size_t)S*H;      // S*H
    float* enc_proj   = enc_states + (size_t)S*H;    // S*A
    float* WcT        = enc_proj + (size_t)S*A;      // H*S
    float* accx_dec   = WcT + (size_t)H*S;           // S*H
    float* h_dec      = accx_dec + (size_t)S*H;      // S*H
    float* dec_proj   = h_dec + (size_t)S*H;         // A
    float* evec       = dec_proj + A;                // S
    int*   bar        = (int*)(evec + S);            // 2048 ints: [0..1023] enc, [1024..2047] dec
    int* bar_e = bar;
    int* bar_d = bar + 1024;

    dim3 b256(256);

    init_bar<<<1, 256, 0, stream>>>(bar);

    // accx_enc = x_enc @ W_enc[:, :V].T + b_enc
    gemm_nt<<<dim3(H/64, S/64), b256, 0, stream>>>(x_enc, V, W_enc, V+H, accx_enc, H, b_enc, S, H, V);
    // accx_dec = x_dec @ W_dec[:, :V].T + b_dec
    gemm_nt<<<dim3(H/64, S/64), b256, 0, stream>>>(x_dec, V, W_dec, V+2*H, accx_dec, H, b_dec, S, H, V);

    // encoder scan (cooperative, persistent)
    {
        const float* We = W_enc; const float* ax = accx_enc; float* st = enc_states; int* bb = bar_e;
        void* args[] = { &We, &ax, &st, &bb };
        hipLaunchCooperativeKernel((void*)enc_scan, dim3(NBLK), dim3(NTHR), args, 0, stream);
    }

    // enc_proj = enc_states @ Wa_enc.T
    gemm_nt<<<dim3(A/64, S/64), b256, 0, stream>>>(enc_states, H, Wa_enc, H, enc_proj, A, nullptr, S, A, H);
    // WcT[i][s] = W_c[i]·enc_states[s]
    gemm_nt<<<dim3(S/64, H/64), b256, 0, stream>>>(W_dec + V, V+2*H, enc_states, H, WcT, S, nullptr, H, S, H);

    // decoder scan (cooperative, persistent)
    {
        const float* wa = Wa_dec; const float* wd = W_dec; const float* epj = enc_proj;
        const float* vv = v_a; const float* wc = WcT; const float* ax = accx_dec;
        const float* est = enc_states; float* hd = h_dec; float* dp = dec_proj; float* ev = evec;
        int* bb = bar_d;
        void* args[] = { &wa, &wd, &epj, &vv, &wc, &ax, &est, &hd, &dp, &ev, &bb };
        hipLaunchCooperativeKernel((void*)dec_scan, dim3(NBLK), dim3(NTHR), args, 0, stream);
    }

    // logits = h_dec @ W_out.T + b_out
    gemm_nt<<<dim3(V/64, S/64), b256, 0, stream>>>(h_dec, H, W_out, H, out, V, b_out, S, V, H);
}